// Round 1
// baseline (566.810 us; speedup 1.0000x reference)
//
#include <hip/hip_runtime.h>
#include <math.h>

#define DI __device__ __forceinline__

typedef __attribute__((ext_vector_type(4))) float  f32x4;
typedef __attribute__((ext_vector_type(4))) short  s16x4;
typedef __attribute__((ext_vector_type(8))) short  s16x8;
typedef __attribute__((ext_vector_type(4))) float  ffrag;
typedef s16x8 bfrag;

constexpr int NT = 8192;   // B*S tokens
constexpr int D  = 4096;
constexpr int NE = 8;      // experts
constexpr int KE = 128;    // E * R
constexpr int KX = D + KE; // 4224 extended K

DI short f2bf(float f) {
  unsigned u = __builtin_bit_cast(unsigned, f);
  u += 0x7FFFu + ((u >> 16) & 1u);   // RNE
  return (short)(u >> 16);
}
DI float bf2f(short h) {
  unsigned u = ((unsigned)(unsigned short)h) << 16;
  return __builtin_bit_cast(float, u);
}

#define GLOAD16(gp, lp)                                                        \
  __builtin_amdgcn_global_load_lds(                                            \
      (const __attribute__((address_space(1))) void*)(gp),                     \
      (__attribute__((address_space(3))) void*)(lp), 16, 0, 0)

// ---------------------------------------------------------------- detect
// flag=0: inputs are fp32.  flag=1: inputs are bf16.
// fp32 N(0,1): exponent field of the dword in [110,140] essentially always.
// bf16-packed dwords: field = (bf16exp&127)<<1 | m6 -> in {0..13} U {230..255}.
__global__ void moe_k_detect(const unsigned* __restrict__ x, int* __restrict__ flag) {
  int l = threadIdx.x;
  int cnt = 0;
  for (int i = l; i < 2048; i += 64) {
    unsigned e = (x[i] >> 23) & 0xFFu;
    cnt += (e >= 110u && e <= 140u) ? 1 : 0;
  }
#pragma unroll
  for (int o = 32; o; o >>= 1) cnt += __shfl_xor(cnt, o);
  if (l == 0) flag[0] = (cnt > 1024) ? 0 : 1;
}

// ---------------------------------------------------------------- prep
// blocks [0,8192):      Wb[d][0:4096]   = bf16(base_W[d][k])
// blocks [8192,8208):   Wb[d][4096+j]   = bf16(2 * lora_B[j][d])   (j = e*16+r)
// blocks [8208,8336):   Abt[j][d]       = bf16(lora_A[e][d][r])
__global__ __launch_bounds__(256)
void moe_k_prep(const void* __restrict__ wp, const void* __restrict__ lAp,
                const void* __restrict__ lBp, const int* __restrict__ flag,
                short* __restrict__ Wb, short* __restrict__ Abt) {
  const bool bf = flag[0] != 0;
  int b = blockIdx.x, t = threadIdx.x;
  if (b < 8192) {
    int tid = b * 256 + t;
    int row = tid >> 9;           // 0..4095
    int col = (tid & 511) << 3;   // 0..4088
    s16x8 o;
    if (!bf) {
      const float* Wf = (const float*)wp;
      f32x4 v0 = *(const f32x4*)&Wf[(size_t)row * 4096 + col];
      f32x4 v1 = *(const f32x4*)&Wf[(size_t)row * 4096 + col + 4];
      o[0] = f2bf(v0[0]); o[1] = f2bf(v0[1]); o[2] = f2bf(v0[2]); o[3] = f2bf(v0[3]);
      o[4] = f2bf(v1[0]); o[5] = f2bf(v1[1]); o[6] = f2bf(v1[2]); o[7] = f2bf(v1[3]);
    } else {
      o = *(const s16x8*)&((const short*)wp)[(size_t)row * 4096 + col];
    }
    *(s16x8*)&Wb[(size_t)row * KX + col] = o;
  } else if (b < 8208) {
    int d = (b - 8192) * 256 + t; // 0..4095
    for (int j0 = 0; j0 < KE; j0 += 8) {
      s16x8 o;
#pragma unroll
      for (int i = 0; i < 8; ++i) {
        float v = bf ? bf2f(((const short*)lBp)[(size_t)(j0 + i) * 4096 + d])
                     : ((const float*)lBp)[(size_t)(j0 + i) * 4096 + d];
        o[i] = f2bf(2.0f * v);    // SCALING folded here
      }
      *(s16x8*)&Wb[(size_t)d * KX + 4096 + j0] = o;
    }
  } else {
    int j = b - 8208;             // 0..127
    int e = j >> 4, r = j & 15;
    for (int d = t; d < 4096; d += 256) {
      size_t src = ((size_t)e * 4096 + d) * 16 + r;
      short v = bf ? ((const short*)lAp)[src] : f2bf(((const float*)lAp)[src]);
      Abt[(size_t)j * 4096 + d] = v;
    }
  }
}

// ---------------------------------------------------------------- x convert + router
// One wave per token: converts x row to bf16 into Xb[:, 0:4096] and computes
// router logits (fp32 accumulation), softmax, top-2, normalized weights.
__global__ __launch_bounds__(256)
void moe_k_xrouter(const void* __restrict__ xp, const void* __restrict__ rp,
                   const int* __restrict__ flag, short* __restrict__ Xb,
                   float* __restrict__ wdense) {
  const bool bf = flag[0] != 0;
  int t = threadIdx.x, wv = t >> 6, l = t & 63;
  int n = blockIdx.x * 4 + wv;
  float acc[NE];
#pragma unroll
  for (int e = 0; e < NE; ++e) acc[e] = 0.f;
  const float* xf = (const float*)xp;
  const short* xh = (const short*)xp;
  const float* rf = (const float*)rp;
  const short* rh = (const short*)rp;
  for (int it = 0; it < 16; ++it) {
    int d = it * 256 + l * 4;
    float x0, x1, x2, x3;
    s16x4 xo;
    if (!bf) {
      f32x4 v = *(const f32x4*)&xf[(size_t)n * D + d];
      x0 = v[0]; x1 = v[1]; x2 = v[2]; x3 = v[3];
      xo[0] = f2bf(x0); xo[1] = f2bf(x1); xo[2] = f2bf(x2); xo[3] = f2bf(x3);
    } else {
      xo = *(const s16x4*)&xh[(size_t)n * D + d];
      x0 = bf2f(xo[0]); x1 = bf2f(xo[1]); x2 = bf2f(xo[2]); x3 = bf2f(xo[3]);
    }
    *(s16x4*)&Xb[(size_t)n * KX + d] = xo;
#pragma unroll
    for (int e = 0; e < NE; ++e) {
      if (!bf) {
        f32x4 w = *(const f32x4*)&rf[(size_t)e * D + d];
        acc[e] += x0 * w[0] + x1 * w[1] + x2 * w[2] + x3 * w[3];
      } else {
        s16x4 w = *(const s16x4*)&rh[(size_t)e * D + d];
        acc[e] += x0 * bf2f(w[0]) + x1 * bf2f(w[1]) + x2 * bf2f(w[2]) + x3 * bf2f(w[3]);
      }
    }
  }
#pragma unroll
  for (int e = 0; e < NE; ++e) {
#pragma unroll
    for (int o = 32; o; o >>= 1) acc[e] += __shfl_xor(acc[e], o);
  }
  // softmax + top-2 (computed redundantly, identically, on all lanes)
  float m = acc[0];
#pragma unroll
  for (int e = 1; e < NE; ++e) m = fmaxf(m, acc[e]);
  float p[NE];
#pragma unroll
  for (int e = 0; e < NE; ++e) p[e] = __expf(acc[e] - m);
  int i1 = 0; float v1 = p[0];
#pragma unroll
  for (int e = 1; e < NE; ++e) { if (p[e] > v1) { v1 = p[e]; i1 = e; } }
  int i2 = 0; float v2 = -1.f;
#pragma unroll
  for (int e = 0; e < NE; ++e) { if (e != i1 && p[e] > v2) { v2 = p[e]; i2 = e; } }
  float inv = 1.f / (v1 + v2);
  if (l < NE) {
    float w = (l == i1) ? v1 * inv : ((l == i2) ? v2 * inv : 0.f);
    wdense[(size_t)n * NE + l] = w;
  }
}

// ---------------------------------------------------------------- mid GEMM
// mid[n][j] = sum_d Xb[n][d] * Abt[j][d]; epilogue: Xb[n][4096+j] = bf16(mid * w[n][j>>4])
// Tile 32(M) x 128(N), BK=32, 4 waves (wave wv owns n-cols [wv*32, wv*32+32)).
__global__ __launch_bounds__(256)
void moe_k_mid(const short* __restrict__ Xb, const short* __restrict__ Abt,
               const float* __restrict__ wdense, short* __restrict__ XbW) {
  __shared__ __align__(16) short As[32 * 32];
  __shared__ __align__(16) short Bs[128 * 32];
  int t = threadIdx.x, wv = t >> 6, l = t & 63;
  int m0 = blockIdx.x * 32;
  ffrag acc[2][2];
#pragma unroll
  for (int i = 0; i < 2; ++i)
#pragma unroll
    for (int j = 0; j < 2; ++j)
#pragma unroll
      for (int q = 0; q < 4; ++q) acc[i][j][q] = 0.f;
  const int r2 = t >> 2, k8 = (t & 3) * 8;
  for (int kt = 0; kt < 128; ++kt) {
    int k0 = kt * 32;
    if (wv < 2) GLOAD16(&Xb[(size_t)(m0 + r2) * KX + k0 + k8], &As[wv * 512]);
    GLOAD16(&Abt[(size_t)r2 * 4096 + k0 + k8], &Bs[wv * 512]);
    GLOAD16(&Abt[(size_t)(64 + r2) * 4096 + k0 + k8], &Bs[2048 + wv * 512]);
    __syncthreads();
    int lr = l & 15, lk = (l >> 4) * 8;
    bfrag a0 = *(const bfrag*)&As[lr * 32 + lk];
    bfrag a1 = *(const bfrag*)&As[(16 + lr) * 32 + lk];
    bfrag b0 = *(const bfrag*)&Bs[(wv * 32 + lr) * 32 + lk];
    bfrag b1 = *(const bfrag*)&Bs[(wv * 32 + 16 + lr) * 32 + lk];
    acc[0][0] = __builtin_amdgcn_mfma_f32_16x16x32_bf16(a0, b0, acc[0][0], 0, 0, 0);
    acc[0][1] = __builtin_amdgcn_mfma_f32_16x16x32_bf16(a0, b1, acc[0][1], 0, 0, 0);
    acc[1][0] = __builtin_amdgcn_mfma_f32_16x16x32_bf16(a1, b0, acc[1][0], 0, 0, 0);
    acc[1][1] = __builtin_amdgcn_mfma_f32_16x16x32_bf16(a1, b1, acc[1][1], 0, 0, 0);
    __syncthreads();
  }
#pragma unroll
  for (int mm = 0; mm < 2; ++mm)
#pragma unroll
    for (int nn = 0; nn < 2; ++nn) {
      int e = wv * 2 + nn;
#pragma unroll
      for (int q = 0; q < 4; ++q) {
        int gr = m0 + mm * 16 + (l >> 4) * 4 + q;
        int j = wv * 32 + nn * 16 + (l & 15);
        float w = wdense[(size_t)gr * NE + e];
        XbW[(size_t)gr * KX + 4096 + j] = f2bf(acc[mm][nn][q] * w);
      }
    }
}

// ---------------------------------------------------------------- main GEMM
// out[n][o] = sum_k Xb[n][k] * Wb[o][k], K = 4224. 128x128 tile, BK=32,
// 4 waves in 2x2, each wave 64x64 (4x4 frags of 16x16x32 bf16 MFMA).
__global__ __launch_bounds__(256)
void moe_k_main(const short* __restrict__ Xb, const short* __restrict__ Wb,
                const int* __restrict__ flag, void* __restrict__ outp) {
  __shared__ __align__(16) short As[128 * 32];
  __shared__ __align__(16) short Bs[128 * 32];
  int t = threadIdx.x, wv = t >> 6, l = t & 63;
  int tm = blockIdx.y * 128, tn = blockIdx.x * 128;
  int wr = wv >> 1, wc = wv & 1;
  ffrag acc[4][4];
#pragma unroll
  for (int i = 0; i < 4; ++i)
#pragma unroll
    for (int j = 0; j < 4; ++j)
#pragma unroll
      for (int q = 0; q < 4; ++q) acc[i][j][q] = 0.f;
  const int r2 = t >> 2, k8 = (t & 3) * 8;
  const size_t rowA  = (size_t)(tm + r2) * KX;
  const size_t rowA2 = (size_t)(tm + 64 + r2) * KX;
  const size_t rowB  = (size_t)(tn + r2) * KX;
  const size_t rowB2 = (size_t)(tn + 64 + r2) * KX;
  for (int kt = 0; kt < KX / 32; ++kt) {  // 132 iterations
    int k0 = kt * 32;
    GLOAD16(&Xb[rowA + k0 + k8],  &As[wv * 512]);
    GLOAD16(&Xb[rowA2 + k0 + k8], &As[2048 + wv * 512]);
    GLOAD16(&Wb[rowB + k0 + k8],  &Bs[wv * 512]);
    GLOAD16(&Wb[rowB2 + k0 + k8], &Bs[2048 + wv * 512]);
    __syncthreads();
    int lr = l & 15, lk = (l >> 4) * 8;
    bfrag a[4], b[4];
#pragma unroll
    for (int i = 0; i < 4; ++i) {
      a[i] = *(const bfrag*)&As[(wr * 64 + i * 16 + lr) * 32 + lk];
      b[i] = *(const bfrag*)&Bs[(wc * 64 + i * 16 + lr) * 32 + lk];
    }
#pragma unroll
    for (int i = 0; i < 4; ++i)
#pragma unroll
      for (int jn = 0; jn < 4; ++jn)
        acc[i][jn] = __builtin_amdgcn_mfma_f32_16x16x32_bf16(a[i], b[jn], acc[i][jn], 0, 0, 0);
    __syncthreads();
  }
  const bool bf = flag[0] != 0;
  float* of = (float*)outp;
  unsigned short* oh = (unsigned short*)outp;
#pragma unroll
  for (int mm = 0; mm < 4; ++mm)
#pragma unroll
    for (int nn = 0; nn < 4; ++nn)
#pragma unroll
      for (int q = 0; q < 4; ++q) {
        int gr = tm + wr * 64 + mm * 16 + (l >> 4) * 4 + q;
        int gc = tn + wc * 64 + nn * 16 + (l & 15);
        float v = acc[mm][nn][q];
        if (!bf) of[(size_t)gr * D + gc] = v;
        else     oh[(size_t)gr * D + gc] = (unsigned short)f2bf(v);
      }
}

// ---------------------------------------------------------------- host
extern "C" void kernel_launch(void* const* d_in, const int* in_sizes, int n_in,
                              void* d_out, int out_size, void* d_ws, size_t ws_size,
                              hipStream_t stream) {
  const void* x  = d_in[0];
  const void* bw = d_in[1];
  const void* rw = d_in[2];
  const void* lA = d_in[3];
  const void* lB = d_in[4];

  char* ws = (char*)d_ws;
  const size_t XB_BYTES  = (size_t)NT * KX * 2;   // 69,206,016
  const size_t WB_BYTES  = (size_t)D * KX * 2;    // 34,603,008
  const size_t ABT_BYTES = (size_t)KE * D * 2;    //  1,048,576
  const size_t WD_BYTES  = (size_t)NT * NE * 4;   //    262,144
  const size_t NEED = 256 + XB_BYTES + WB_BYTES + ABT_BYTES + WD_BYTES;
  if (ws_size < NEED) return;  // cannot run without scratch

  int*   flag   = (int*)ws;
  short* Xb     = (short*)(ws + 256);
  short* Wb     = (short*)(ws + 256 + XB_BYTES);
  short* Abt    = (short*)(ws + 256 + XB_BYTES + WB_BYTES);
  float* wdense = (float*)(ws + 256 + XB_BYTES + WB_BYTES + ABT_BYTES);

  hipLaunchKernelGGL(moe_k_detect, dim3(1), dim3(64), 0, stream,
                     (const unsigned*)x, flag);
  hipLaunchKernelGGL(moe_k_prep, dim3(8336), dim3(256), 0, stream,
                     bw, lA, lB, flag, Wb, Abt);
  hipLaunchKernelGGL(moe_k_xrouter, dim3(NT / 4), dim3(256), 0, stream,
                     x, rw, flag, Xb, wdense);
  hipLaunchKernelGGL(moe_k_mid, dim3(NT / 32), dim3(256), 0, stream,
                     Xb, Abt, wdense, Xb);
  hipLaunchKernelGGL(moe_k_main, dim3(D / 128, NT / 128), dim3(256), 0, stream,
                     Xb, Wb, flag, d_out);
}

// Round 2
// 539.635 us; speedup vs baseline: 1.0504x; 1.0504x over previous
//
#include <hip/hip_runtime.h>
#include <math.h>

#define DI __device__ __forceinline__

typedef __attribute__((ext_vector_type(4))) float  f32x4;
typedef __attribute__((ext_vector_type(4))) short  s16x4;
typedef __attribute__((ext_vector_type(8))) short  s16x8;
typedef __attribute__((ext_vector_type(4))) float  ffrag;
typedef s16x8 bfrag;

constexpr int NT = 8192;   // B*S tokens
constexpr int D  = 4096;
constexpr int NE = 8;      // experts
constexpr int KE = 128;    // E * R
constexpr int KX = D + KE; // 4224 extended K

DI short f2bf(float f) {
  unsigned u = __builtin_bit_cast(unsigned, f);
  u += 0x7FFFu + ((u >> 16) & 1u);   // RNE
  return (short)(u >> 16);
}
DI float bf2f(short h) {
  unsigned u = ((unsigned)(unsigned short)h) << 16;
  return __builtin_bit_cast(float, u);
}

#define GLOAD16(gp, lp)                                                        \
  __builtin_amdgcn_global_load_lds(                                            \
      (const __attribute__((address_space(1))) void*)(gp),                     \
      (__attribute__((address_space(3))) void*)(lp), 16, 0, 0)

// ---------------------------------------------------------------- detect
__global__ void moe_k_detect(const unsigned* __restrict__ x, int* __restrict__ flag) {
  int l = threadIdx.x;
  int cnt = 0;
  for (int i = l; i < 2048; i += 64) {
    unsigned e = (x[i] >> 23) & 0xFFu;
    cnt += (e >= 110u && e <= 140u) ? 1 : 0;
  }
#pragma unroll
  for (int o = 32; o; o >>= 1) cnt += __shfl_xor(cnt, o);
  if (l == 0) flag[0] = (cnt > 1024) ? 0 : 1;
}

// ---------------------------------------------------------------- prep
__global__ __launch_bounds__(256)
void moe_k_prep(const void* __restrict__ wp, const void* __restrict__ lAp,
                const void* __restrict__ lBp, const int* __restrict__ flag,
                short* __restrict__ Wb, short* __restrict__ Abt) {
  const bool bf = flag[0] != 0;
  int b = blockIdx.x, t = threadIdx.x;
  if (b < 8192) {
    int tid = b * 256 + t;
    int row = tid >> 9;           // 0..4095
    int col = (tid & 511) << 3;   // 0..4088
    s16x8 o;
    if (!bf) {
      const float* Wf = (const float*)wp;
      f32x4 v0 = *(const f32x4*)&Wf[(size_t)row * 4096 + col];
      f32x4 v1 = *(const f32x4*)&Wf[(size_t)row * 4096 + col + 4];
      o[0] = f2bf(v0[0]); o[1] = f2bf(v0[1]); o[2] = f2bf(v0[2]); o[3] = f2bf(v0[3]);
      o[4] = f2bf(v1[0]); o[5] = f2bf(v1[1]); o[6] = f2bf(v1[2]); o[7] = f2bf(v1[3]);
    } else {
      o = *(const s16x8*)&((const short*)wp)[(size_t)row * 4096 + col];
    }
    *(s16x8*)&Wb[(size_t)row * KX + col] = o;
  } else if (b < 8208) {
    int d = (b - 8192) * 256 + t; // 0..4095
    for (int j0 = 0; j0 < KE; j0 += 8) {
      s16x8 o;
#pragma unroll
      for (int i = 0; i < 8; ++i) {
        float v = bf ? bf2f(((const short*)lBp)[(size_t)(j0 + i) * 4096 + d])
                     : ((const float*)lBp)[(size_t)(j0 + i) * 4096 + d];
        o[i] = f2bf(2.0f * v);    // SCALING folded here
      }
      *(s16x8*)&Wb[(size_t)d * KX + 4096 + j0] = o;
    }
  } else {
    int j = b - 8208;             // 0..127
    int e = j >> 4, r = j & 15;
    for (int d = t; d < 4096; d += 256) {
      size_t src = ((size_t)e * 4096 + d) * 16 + r;
      short v = bf ? ((const short*)lAp)[src] : f2bf(((const float*)lAp)[src]);
      Abt[(size_t)j * 4096 + d] = v;
    }
  }
}

// ---------------------------------------------------------------- x convert + router
__global__ __launch_bounds__(256)
void moe_k_xrouter(const void* __restrict__ xp, const void* __restrict__ rp,
                   const int* __restrict__ flag, short* __restrict__ Xb,
                   float* __restrict__ wdense) {
  const bool bf = flag[0] != 0;
  int t = threadIdx.x, wv = t >> 6, l = t & 63;
  int n = blockIdx.x * 4 + wv;
  float acc[NE];
#pragma unroll
  for (int e = 0; e < NE; ++e) acc[e] = 0.f;
  const float* xf = (const float*)xp;
  const short* xh = (const short*)xp;
  const float* rf = (const float*)rp;
  const short* rh = (const short*)rp;
  for (int it = 0; it < 16; ++it) {
    int d = it * 256 + l * 4;
    float x0, x1, x2, x3;
    s16x4 xo;
    if (!bf) {
      f32x4 v = *(const f32x4*)&xf[(size_t)n * D + d];
      x0 = v[0]; x1 = v[1]; x2 = v[2]; x3 = v[3];
      xo[0] = f2bf(x0); xo[1] = f2bf(x1); xo[2] = f2bf(x2); xo[3] = f2bf(x3);
    } else {
      xo = *(const s16x4*)&xh[(size_t)n * D + d];
      x0 = bf2f(xo[0]); x1 = bf2f(xo[1]); x2 = bf2f(xo[2]); x3 = bf2f(xo[3]);
    }
    *(s16x4*)&Xb[(size_t)n * KX + d] = xo;
#pragma unroll
    for (int e = 0; e < NE; ++e) {
      if (!bf) {
        f32x4 w = *(const f32x4*)&rf[(size_t)e * D + d];
        acc[e] += x0 * w[0] + x1 * w[1] + x2 * w[2] + x3 * w[3];
      } else {
        s16x4 w = *(const s16x4*)&rh[(size_t)e * D + d];
        acc[e] += x0 * bf2f(w[0]) + x1 * bf2f(w[1]) + x2 * bf2f(w[2]) + x3 * bf2f(w[3]);
      }
    }
  }
#pragma unroll
  for (int e = 0; e < NE; ++e) {
#pragma unroll
    for (int o = 32; o; o >>= 1) acc[e] += __shfl_xor(acc[e], o);
  }
  float m = acc[0];
#pragma unroll
  for (int e = 1; e < NE; ++e) m = fmaxf(m, acc[e]);
  float p[NE];
#pragma unroll
  for (int e = 0; e < NE; ++e) p[e] = __expf(acc[e] - m);
  int i1 = 0; float v1 = p[0];
#pragma unroll
  for (int e = 1; e < NE; ++e) { if (p[e] > v1) { v1 = p[e]; i1 = e; } }
  int i2 = 0; float v2 = -1.f;
#pragma unroll
  for (int e = 0; e < NE; ++e) { if (e != i1 && p[e] > v2) { v2 = p[e]; i2 = e; } }
  float inv = 1.f / (v1 + v2);
  if (l < NE) {
    float w = (l == i1) ? v1 * inv : ((l == i2) ? v2 * inv : 0.f);
    wdense[(size_t)n * NE + l] = w;
  }
}

// ---------------------------------------------------------------- mid GEMM
__global__ __launch_bounds__(256)
void moe_k_mid(const short* __restrict__ Xb, const short* __restrict__ Abt,
               const float* __restrict__ wdense, short* __restrict__ XbW) {
  __shared__ __align__(16) short As[32 * 32];
  __shared__ __align__(16) short Bs[128 * 32];
  int t = threadIdx.x, wv = t >> 6, l = t & 63;
  int m0 = blockIdx.x * 32;
  ffrag acc[2][2];
#pragma unroll
  for (int i = 0; i < 2; ++i)
#pragma unroll
    for (int j = 0; j < 2; ++j)
#pragma unroll
      for (int q = 0; q < 4; ++q) acc[i][j][q] = 0.f;
  const int r2 = t >> 2, k8 = (t & 3) * 8;
  for (int kt = 0; kt < 128; ++kt) {
    int k0 = kt * 32;
    if (wv < 2) GLOAD16(&Xb[(size_t)(m0 + r2) * KX + k0 + k8], &As[wv * 512]);
    GLOAD16(&Abt[(size_t)r2 * 4096 + k0 + k8], &Bs[wv * 512]);
    GLOAD16(&Abt[(size_t)(64 + r2) * 4096 + k0 + k8], &Bs[2048 + wv * 512]);
    __syncthreads();
    int lr = l & 15, lk = (l >> 4) * 8;
    bfrag a0 = *(const bfrag*)&As[lr * 32 + lk];
    bfrag a1 = *(const bfrag*)&As[(16 + lr) * 32 + lk];
    bfrag b0 = *(const bfrag*)&Bs[(wv * 32 + lr) * 32 + lk];
    bfrag b1 = *(const bfrag*)&Bs[(wv * 32 + 16 + lr) * 32 + lk];
    acc[0][0] = __builtin_amdgcn_mfma_f32_16x16x32_bf16(a0, b0, acc[0][0], 0, 0, 0);
    acc[0][1] = __builtin_amdgcn_mfma_f32_16x16x32_bf16(a0, b1, acc[0][1], 0, 0, 0);
    acc[1][0] = __builtin_amdgcn_mfma_f32_16x16x32_bf16(a1, b0, acc[1][0], 0, 0, 0);
    acc[1][1] = __builtin_amdgcn_mfma_f32_16x16x32_bf16(a1, b1, acc[1][1], 0, 0, 0);
    __syncthreads();
  }
#pragma unroll
  for (int mm = 0; mm < 2; ++mm)
#pragma unroll
    for (int nn = 0; nn < 2; ++nn) {
      int e = wv * 2 + nn;
#pragma unroll
      for (int q = 0; q < 4; ++q) {
        int gr = m0 + mm * 16 + (l >> 4) * 4 + q;
        int j = wv * 32 + nn * 16 + (l & 15);
        float w = wdense[(size_t)gr * NE + e];
        XbW[(size_t)gr * KX + 4096 + j] = f2bf(acc[mm][nn][q] * w);
      }
    }
}

// ---------------------------------------------------------------- main GEMM (8-phase-style)
// out[n][o] = sum_k Xb[n][k] * Wb[o][k], K = 4224.
// 256x256 tile, BK=32, 512 threads = 8 waves (2 M x 4 N), each wave 128x64.
// LDS: 4-deep K-tile ring (A 16KB + B 16KB per tile = 128KB), kc-major layout
// [kc(4)][row(256)][8 bf16] -> conflict-free ds_read_b128 fragment reads.
// Counted vmcnt(8) at tile boundaries (3-tile prefetch lead), raw s_barrier,
// setprio(1) around each 16-MFMA cluster.
__global__ __launch_bounds__(512, 2)
void moe_k_main8(const short* __restrict__ Xb, const short* __restrict__ Wb,
                 const int* __restrict__ flag, void* __restrict__ outp) {
  __shared__ __align__(16) short LDS[65536];  // 128 KiB
  const int t = threadIdx.x;
  const int l = t & 63;
  const int wv = t >> 6;
  const int wr = wv >> 2;        // 0..1  (M group: 128 rows)
  const int wc = wv & 3;         // 0..3  (N group: 64 cols)
  const int lr = l & 15;
  const int kc = l >> 4;         // 0..3

  int wg = blockIdx.x;                       // 512 wgs, %8==0 -> simple XCD swizzle
  int swz = (wg & 7) * 64 + (wg >> 3);
  const int tm = (swz >> 4) * 256;           // 32 M blocks
  const int tn = (swz & 15) * 256;           // 16 N blocks

  ffrag acc[8][4];
#pragma unroll
  for (int i = 0; i < 8; ++i)
#pragma unroll
    for (int j = 0; j < 4; ++j)
#pragma unroll
      for (int q = 0; q < 4; ++q) acc[i][j][q] = 0.f;

  // stage: LDS chunk c (16B) holds global (row=c&255, kelems (c>>8)*8..+8)
#define STAGE_A(kt_)                                                           \
  do {                                                                         \
    int _k0 = (kt_) * 32, _b = ((kt_) & 3) * 16384;                            \
    _Pragma("unroll")                                                          \
    for (int _i = 0; _i < 2; ++_i) {                                           \
      int _c = _i * 512 + t;                                                   \
      GLOAD16(&Xb[(size_t)(tm + (_c & 255)) * KX + _k0 + (_c >> 8) * 8],       \
              &LDS[_b + _c * 8]);                                              \
    }                                                                          \
  } while (0)
#define STAGE_B(kt_)                                                           \
  do {                                                                         \
    int _k0 = (kt_) * 32, _b = ((kt_) & 3) * 16384 + 8192;                     \
    _Pragma("unroll")                                                          \
    for (int _i = 0; _i < 2; ++_i) {                                           \
      int _c = _i * 512 + t;                                                   \
      GLOAD16(&Wb[(size_t)(tn + (_c & 255)) * KX + _k0 + (_c >> 8) * 8],       \
              &LDS[_b + _c * 8]);                                              \
    }                                                                          \
  } while (0)

  // prologue: stage tiles 0,1,2 (oldest-first; 4 loads per tile per thread)
  STAGE_A(0); STAGE_B(0);
  STAGE_A(1); STAGE_B(1);
  STAGE_A(2); STAGE_B(2);

  constexpr int NKT = KX / 32;  // 132

#define MFMA_ROW(mi, av)                                                           \
  acc[mi][0] = __builtin_amdgcn_mfma_f32_16x16x32_bf16(av, b0, acc[mi][0], 0, 0, 0); \
  acc[mi][1] = __builtin_amdgcn_mfma_f32_16x16x32_bf16(av, b1, acc[mi][1], 0, 0, 0); \
  acc[mi][2] = __builtin_amdgcn_mfma_f32_16x16x32_bf16(av, b2, acc[mi][2], 0, 0, 0); \
  acc[mi][3] = __builtin_amdgcn_mfma_f32_16x16x32_bf16(av, b3, acc[mi][3], 0, 0, 0);

  for (int kt = 0; kt < NKT; ++kt) {
    // residency wait for tile kt: newest 8 in-flight loads = tiles kt+1,kt+2
    if (kt + 2 < NKT)      asm volatile("s_waitcnt vmcnt(8)" ::: "memory");
    else if (kt + 1 < NKT) asm volatile("s_waitcnt vmcnt(4)" ::: "memory");
    else                   asm volatile("s_waitcnt vmcnt(0)" ::: "memory");
    __builtin_amdgcn_s_barrier();
    asm volatile("" ::: "memory");  // no LDS-read hoisting above the barrier

    const int bufs = (kt & 3) * 16384;
    const short* Ab = &LDS[bufs + kc * 2048 + (wr * 128 + lr) * 8];
    const short* Bb = &LDS[bufs + 8192 + kc * 2048 + (wc * 64 + lr) * 8];

    // ---- phase 0: m0..3 x n0..3
    bfrag b0 = *(const bfrag*)&Bb[0];
    bfrag b1 = *(const bfrag*)&Bb[128];
    bfrag b2 = *(const bfrag*)&Bb[256];
    bfrag b3 = *(const bfrag*)&Bb[384];
    bfrag a0 = *(const bfrag*)&Ab[0];
    bfrag a1 = *(const bfrag*)&Ab[128];
    bfrag a2 = *(const bfrag*)&Ab[256];
    bfrag a3 = *(const bfrag*)&Ab[384];
    if (kt + 3 < NKT) STAGE_A(kt + 3);
    __builtin_amdgcn_s_setprio(1);
    MFMA_ROW(0, a0) MFMA_ROW(1, a1) MFMA_ROW(2, a2) MFMA_ROW(3, a3)
    __builtin_amdgcn_s_setprio(0);
    __builtin_amdgcn_s_barrier();
    asm volatile("" ::: "memory");

    // ---- phase 1: m4..7 x n0..3 (b reused)
    bfrag a4 = *(const bfrag*)&Ab[512];
    bfrag a5 = *(const bfrag*)&Ab[640];
    bfrag a6 = *(const bfrag*)&Ab[768];
    bfrag a7 = *(const bfrag*)&Ab[896];
    if (kt + 3 < NKT) STAGE_B(kt + 3);
    __builtin_amdgcn_s_setprio(1);
    MFMA_ROW(4, a4) MFMA_ROW(5, a5) MFMA_ROW(6, a6) MFMA_ROW(7, a7)
    __builtin_amdgcn_s_setprio(0);
  }

  const bool bf = flag[0] != 0;
  float* of = (float*)outp;
  unsigned short* oh = (unsigned short*)outp;
#pragma unroll
  for (int m = 0; m < 8; ++m)
#pragma unroll
    for (int n = 0; n < 4; ++n)
#pragma unroll
      for (int q = 0; q < 4; ++q) {
        int gr = tm + wr * 128 + m * 16 + kc * 4 + q;
        int gc = tn + wc * 64 + n * 16 + lr;
        float v = acc[m][n][q];
        if (!bf) of[(size_t)gr * D + gc] = v;
        else     oh[(size_t)gr * D + gc] = (unsigned short)f2bf(v);
      }
#undef STAGE_A
#undef STAGE_B
#undef MFMA_ROW
}

// ---------------------------------------------------------------- host
extern "C" void kernel_launch(void* const* d_in, const int* in_sizes, int n_in,
                              void* d_out, int out_size, void* d_ws, size_t ws_size,
                              hipStream_t stream) {
  const void* x  = d_in[0];
  const void* bw = d_in[1];
  const void* rw = d_in[2];
  const void* lA = d_in[3];
  const void* lB = d_in[4];

  char* ws = (char*)d_ws;
  const size_t XB_BYTES  = (size_t)NT * KX * 2;   // 69,206,016
  const size_t WB_BYTES  = (size_t)D * KX * 2;    // 34,603,008
  const size_t ABT_BYTES = (size_t)KE * D * 2;    //  1,048,576
  const size_t WD_BYTES  = (size_t)NT * NE * 4;   //    262,144
  const size_t NEED = 256 + XB_BYTES + WB_BYTES + ABT_BYTES + WD_BYTES;
  if (ws_size < NEED) return;  // cannot run without scratch

  int*   flag   = (int*)ws;
  short* Xb     = (short*)(ws + 256);
  short* Wb     = (short*)(ws + 256 + XB_BYTES);
  short* Abt    = (short*)(ws + 256 + XB_BYTES + WB_BYTES);
  float* wdense = (float*)(ws + 256 + XB_BYTES + WB_BYTES + ABT_BYTES);

  hipLaunchKernelGGL(moe_k_detect, dim3(1), dim3(64), 0, stream,
                     (const unsigned*)x, flag);
  hipLaunchKernelGGL(moe_k_prep, dim3(8336), dim3(256), 0, stream,
                     bw, lA, lB, flag, Wb, Abt);
  hipLaunchKernelGGL(moe_k_xrouter, dim3(NT / 4), dim3(256), 0, stream,
                     x, rw, flag, Xb, wdense);
  hipLaunchKernelGGL(moe_k_mid, dim3(NT / 32), dim3(256), 0, stream,
                     Xb, Abt, wdense, Xb);
  hipLaunchKernelGGL(moe_k_main8, dim3(512), dim3(512), 0, stream,
                     Xb, Wb, flag, d_out);
}

// Round 3
// 429.062 us; speedup vs baseline: 1.3210x; 1.2577x over previous
//
#include <hip/hip_runtime.h>
#include <math.h>

#define DI __device__ __forceinline__

typedef __attribute__((ext_vector_type(4))) float  f32x4;
typedef __attribute__((ext_vector_type(4))) short  s16x4;
typedef __attribute__((ext_vector_type(8))) short  s16x8;
typedef __attribute__((ext_vector_type(4))) float  ffrag;
typedef s16x8 bfrag;

constexpr int NT = 8192;   // B*S tokens
constexpr int D  = 4096;
constexpr int NE = 8;      // experts
constexpr int KE = 128;    // E * R
constexpr int KX = D + KE; // 4224 extended K

DI short f2bf(float f) {
  unsigned u = __builtin_bit_cast(unsigned, f);
  u += 0x7FFFu + ((u >> 16) & 1u);   // RNE
  return (short)(u >> 16);
}
DI float bf2f(short h) {
  unsigned u = ((unsigned)(unsigned short)h) << 16;
  return __builtin_bit_cast(float, u);
}

#define GLOAD16(gp, lp)                                                        \
  __builtin_amdgcn_global_load_lds(                                            \
      (const __attribute__((address_space(1))) void*)(gp),                     \
      (__attribute__((address_space(3))) void*)(lp), 16, 0, 0)

// ---------------------------------------------------------------- detect
__global__ void moe_k_detect(const unsigned* __restrict__ x, int* __restrict__ flag) {
  int l = threadIdx.x;
  int cnt = 0;
  for (int i = l; i < 2048; i += 64) {
    unsigned e = (x[i] >> 23) & 0xFFu;
    cnt += (e >= 110u && e <= 140u) ? 1 : 0;
  }
#pragma unroll
  for (int o = 32; o; o >>= 1) cnt += __shfl_xor(cnt, o);
  if (l == 0) flag[0] = (cnt > 1024) ? 0 : 1;
}

// ---------------------------------------------------------------- prep
__global__ __launch_bounds__(256)
void moe_k_prep(const void* __restrict__ wp, const void* __restrict__ lAp,
                const void* __restrict__ lBp, const int* __restrict__ flag,
                short* __restrict__ Wb, short* __restrict__ Abt) {
  const bool bf = flag[0] != 0;
  int b = blockIdx.x, t = threadIdx.x;
  if (b < 8192) {
    int tid = b * 256 + t;
    int row = tid >> 9;           // 0..4095
    int col = (tid & 511) << 3;   // 0..4088
    s16x8 o;
    if (!bf) {
      const float* Wf = (const float*)wp;
      f32x4 v0 = *(const f32x4*)&Wf[(size_t)row * 4096 + col];
      f32x4 v1 = *(const f32x4*)&Wf[(size_t)row * 4096 + col + 4];
      o[0] = f2bf(v0[0]); o[1] = f2bf(v0[1]); o[2] = f2bf(v0[2]); o[3] = f2bf(v0[3]);
      o[4] = f2bf(v1[0]); o[5] = f2bf(v1[1]); o[6] = f2bf(v1[2]); o[7] = f2bf(v1[3]);
    } else {
      o = *(const s16x8*)&((const short*)wp)[(size_t)row * 4096 + col];
    }
    *(s16x8*)&Wb[(size_t)row * KX + col] = o;
  } else if (b < 8208) {
    int d = (b - 8192) * 256 + t; // 0..4095
    for (int j0 = 0; j0 < KE; j0 += 8) {
      s16x8 o;
#pragma unroll
      for (int i = 0; i < 8; ++i) {
        float v = bf ? bf2f(((const short*)lBp)[(size_t)(j0 + i) * 4096 + d])
                     : ((const float*)lBp)[(size_t)(j0 + i) * 4096 + d];
        o[i] = f2bf(2.0f * v);    // SCALING folded here
      }
      *(s16x8*)&Wb[(size_t)d * KX + 4096 + j0] = o;
    }
  } else {
    int j = b - 8208;             // 0..127
    int e = j >> 4, r = j & 15;
    for (int d = t; d < 4096; d += 256) {
      size_t src = ((size_t)e * 4096 + d) * 16 + r;
      short v = bf ? ((const short*)lAp)[src] : f2bf(((const float*)lAp)[src]);
      Abt[(size_t)j * 4096 + d] = v;
    }
  }
}

// ---------------------------------------------------------------- x convert + router
__global__ __launch_bounds__(256)
void moe_k_xrouter(const void* __restrict__ xp, const void* __restrict__ rp,
                   const int* __restrict__ flag, short* __restrict__ Xb,
                   float* __restrict__ wdense) {
  const bool bf = flag[0] != 0;
  int t = threadIdx.x, wv = t >> 6, l = t & 63;
  int n = blockIdx.x * 4 + wv;
  float acc[NE];
#pragma unroll
  for (int e = 0; e < NE; ++e) acc[e] = 0.f;
  const float* xf = (const float*)xp;
  const short* xh = (const short*)xp;
  const float* rf = (const float*)rp;
  const short* rh = (const short*)rp;
  for (int it = 0; it < 16; ++it) {
    int d = it * 256 + l * 4;
    float x0, x1, x2, x3;
    s16x4 xo;
    if (!bf) {
      f32x4 v = *(const f32x4*)&xf[(size_t)n * D + d];
      x0 = v[0]; x1 = v[1]; x2 = v[2]; x3 = v[3];
      xo[0] = f2bf(x0); xo[1] = f2bf(x1); xo[2] = f2bf(x2); xo[3] = f2bf(x3);
    } else {
      xo = *(const s16x4*)&xh[(size_t)n * D + d];
      x0 = bf2f(xo[0]); x1 = bf2f(xo[1]); x2 = bf2f(xo[2]); x3 = bf2f(xo[3]);
    }
    *(s16x4*)&Xb[(size_t)n * KX + d] = xo;
#pragma unroll
    for (int e = 0; e < NE; ++e) {
      if (!bf) {
        f32x4 w = *(const f32x4*)&rf[(size_t)e * D + d];
        acc[e] += x0 * w[0] + x1 * w[1] + x2 * w[2] + x3 * w[3];
      } else {
        s16x4 w = *(const s16x4*)&rh[(size_t)e * D + d];
        acc[e] += x0 * bf2f(w[0]) + x1 * bf2f(w[1]) + x2 * bf2f(w[2]) + x3 * bf2f(w[3]);
      }
    }
  }
#pragma unroll
  for (int e = 0; e < NE; ++e) {
#pragma unroll
    for (int o = 32; o; o >>= 1) acc[e] += __shfl_xor(acc[e], o);
  }
  float m = acc[0];
#pragma unroll
  for (int e = 1; e < NE; ++e) m = fmaxf(m, acc[e]);
  float p[NE];
#pragma unroll
  for (int e = 0; e < NE; ++e) p[e] = __expf(acc[e] - m);
  int i1 = 0; float v1 = p[0];
#pragma unroll
  for (int e = 1; e < NE; ++e) { if (p[e] > v1) { v1 = p[e]; i1 = e; } }
  int i2 = 0; float v2 = -1.f;
#pragma unroll
  for (int e = 0; e < NE; ++e) { if (e != i1 && p[e] > v2) { v2 = p[e]; i2 = e; } }
  float inv = 1.f / (v1 + v2);
  if (l < NE) {
    float w = (l == i1) ? v1 * inv : ((l == i2) ? v2 * inv : 0.f);
    wdense[(size_t)n * NE + l] = w;
  }
}

// ---------------------------------------------------------------- mid GEMM
__global__ __launch_bounds__(256)
void moe_k_mid(const short* __restrict__ Xb, const short* __restrict__ Abt,
               const float* __restrict__ wdense, short* __restrict__ XbW) {
  __shared__ __align__(16) short As[32 * 32];
  __shared__ __align__(16) short Bs[128 * 32];
  int t = threadIdx.x, wv = t >> 6, l = t & 63;
  int m0 = blockIdx.x * 32;
  ffrag acc[2][2];
#pragma unroll
  for (int i = 0; i < 2; ++i)
#pragma unroll
    for (int j = 0; j < 2; ++j)
#pragma unroll
      for (int q = 0; q < 4; ++q) acc[i][j][q] = 0.f;
  const int r2 = t >> 2, k8 = (t & 3) * 8;
  for (int kt = 0; kt < 128; ++kt) {
    int k0 = kt * 32;
    if (wv < 2) GLOAD16(&Xb[(size_t)(m0 + r2) * KX + k0 + k8], &As[wv * 512]);
    GLOAD16(&Abt[(size_t)r2 * 4096 + k0 + k8], &Bs[wv * 512]);
    GLOAD16(&Abt[(size_t)(64 + r2) * 4096 + k0 + k8], &Bs[2048 + wv * 512]);
    __syncthreads();
    int lr = l & 15, lk = (l >> 4) * 8;
    bfrag a0 = *(const bfrag*)&As[lr * 32 + lk];
    bfrag a1 = *(const bfrag*)&As[(16 + lr) * 32 + lk];
    bfrag b0 = *(const bfrag*)&Bs[(wv * 32 + lr) * 32 + lk];
    bfrag b1 = *(const bfrag*)&Bs[(wv * 32 + 16 + lr) * 32 + lk];
    acc[0][0] = __builtin_amdgcn_mfma_f32_16x16x32_bf16(a0, b0, acc[0][0], 0, 0, 0);
    acc[0][1] = __builtin_amdgcn_mfma_f32_16x16x32_bf16(a0, b1, acc[0][1], 0, 0, 0);
    acc[1][0] = __builtin_amdgcn_mfma_f32_16x16x32_bf16(a1, b0, acc[1][0], 0, 0, 0);
    acc[1][1] = __builtin_amdgcn_mfma_f32_16x16x32_bf16(a1, b1, acc[1][1], 0, 0, 0);
    __syncthreads();
  }
#pragma unroll
  for (int mm = 0; mm < 2; ++mm)
#pragma unroll
    for (int nn = 0; nn < 2; ++nn) {
      int e = wv * 2 + nn;
#pragma unroll
      for (int q = 0; q < 4; ++q) {
        int gr = m0 + mm * 16 + (l >> 4) * 4 + q;
        int j = wv * 32 + nn * 16 + (l & 15);
        float w = wdense[(size_t)gr * NE + e];
        XbW[(size_t)gr * KX + 4096 + j] = f2bf(acc[mm][nn][q] * w);
      }
    }
}

// ---------------------------------------------------------------- main GEMM (8-phase-style)
// out[n][o] = sum_k Xb[n][k] * Wb[o][k], K = 4224.
// 256x256 tile, BK=32, 512 threads = 8 waves (2 M x 4 N), each wave 128x64.
// LDS per K-tile: A[256 rows][4 slots of 16B] linear (32KB A+B), ring-4.
// Slot s of row r holds global k-chunk kc = s ^ ((r>>1)&3):
//   - global side: the 4 lanes of a row read a permuted-but-complete 64B
//     row segment -> full coalescing (fix for r1's 16B-scatter staging);
//   - LDS side: fragment read bank-base (l&1)*16 + (kc^((r>>1)&3))*4 covers
//     all 32 banks exactly 2-way -> conflict-free (m136: 2-way is free).
// Same involution applied on source and read (rule #21). Sync skeleton
// identical to r1 (verified): counted vmcnt(8)/tile, raw s_barrier, setprio.
__global__ __launch_bounds__(512, 2)
void moe_k_main8(const short* __restrict__ Xb, const short* __restrict__ Wb,
                 const int* __restrict__ flag, void* __restrict__ outp) {
  __shared__ __align__(16) short LDS[65536];  // 128 KiB
  const int t = threadIdx.x;
  const int l = t & 63;
  const int wv = t >> 6;
  const int wr = wv >> 2;        // 0..1  (M group: 128 rows)
  const int wc = wv & 3;         // 0..3  (N group: 64 cols)
  const int lr = l & 15;
  const int kq = l >> 4;         // 0..3  (k-chunk group)

  int wg = blockIdx.x;                       // 512 wgs, %8==0 -> simple XCD swizzle
  int swz = (wg & 7) * 64 + (wg >> 3);
  const int tm = (swz >> 4) * 256;           // 32 M blocks
  const int tn = (swz & 15) * 256;           // 16 N blocks

  ffrag acc[8][4];
#pragma unroll
  for (int i = 0; i < 8; ++i)
#pragma unroll
    for (int j = 0; j < 4; ++j)
#pragma unroll
      for (int q = 0; q < 4; ++q) acc[i][j][q] = 0.f;

  // staging: chunk c -> row = c>>2, slot s = c&3, global kc = s ^ ((row>>1)&3)
#define STAGE_A(kt_)                                                           \
  do {                                                                         \
    int _k0 = (kt_) * 32, _b = ((kt_) & 3) * 16384;                            \
    _Pragma("unroll")                                                          \
    for (int _i = 0; _i < 2; ++_i) {                                           \
      int _c = _i * 512 + t;                                                   \
      int _r = _c >> 2;                                                        \
      int _kc = (_c & 3) ^ ((_r >> 1) & 3);                                    \
      GLOAD16(&Xb[(size_t)(tm + _r) * KX + _k0 + _kc * 8], &LDS[_b + _c * 8]); \
    }                                                                          \
  } while (0)
#define STAGE_B(kt_)                                                           \
  do {                                                                         \
    int _k0 = (kt_) * 32, _b = ((kt_) & 3) * 16384 + 8192;                     \
    _Pragma("unroll")                                                          \
    for (int _i = 0; _i < 2; ++_i) {                                           \
      int _c = _i * 512 + t;                                                   \
      int _r = _c >> 2;                                                        \
      int _kc = (_c & 3) ^ ((_r >> 1) & 3);                                    \
      GLOAD16(&Wb[(size_t)(tn + _r) * KX + _k0 + _kc * 8], &LDS[_b + _c * 8]); \
    }                                                                          \
  } while (0)

  // prologue: stage tiles 0,1,2
  STAGE_A(0); STAGE_B(0);
  STAGE_A(1); STAGE_B(1);
  STAGE_A(2); STAGE_B(2);

  constexpr int NKT = KX / 32;  // 132

  // per-lane constant swizzled slot: frag rows differ by multiples of 16,
  // so (row>>1)&3 == (lr>>1)&3 for every fragment this lane reads.
  const int kx = kq ^ ((lr >> 1) & 3);           // swizzled 16B slot index
  const int aofs = (wr * 128 + lr) * 32 + kx * 8;        // shorts
  const int bofs = 8192 + (wc * 64 + lr) * 32 + kx * 8;  // shorts

#define MFMA_ROW(mi, av)                                                           \
  acc[mi][0] = __builtin_amdgcn_mfma_f32_16x16x32_bf16(av, b0, acc[mi][0], 0, 0, 0); \
  acc[mi][1] = __builtin_amdgcn_mfma_f32_16x16x32_bf16(av, b1, acc[mi][1], 0, 0, 0); \
  acc[mi][2] = __builtin_amdgcn_mfma_f32_16x16x32_bf16(av, b2, acc[mi][2], 0, 0, 0); \
  acc[mi][3] = __builtin_amdgcn_mfma_f32_16x16x32_bf16(av, b3, acc[mi][3], 0, 0, 0);

  for (int kt = 0; kt < NKT; ++kt) {
    // residency wait for tile kt
    if (kt + 2 < NKT)      asm volatile("s_waitcnt vmcnt(8)" ::: "memory");
    else if (kt + 1 < NKT) asm volatile("s_waitcnt vmcnt(4)" ::: "memory");
    else                   asm volatile("s_waitcnt vmcnt(0)" ::: "memory");
    __builtin_amdgcn_s_barrier();
    asm volatile("" ::: "memory");

    const int bufs = (kt & 3) * 16384;
    const short* Ab = &LDS[bufs + aofs];
    const short* Bb = &LDS[bufs + bofs];

    // ---- phase 0: m0..3 x n0..3
    bfrag b0 = *(const bfrag*)&Bb[0];
    bfrag b1 = *(const bfrag*)&Bb[512];
    bfrag b2 = *(const bfrag*)&Bb[1024];
    bfrag b3 = *(const bfrag*)&Bb[1536];
    bfrag a0 = *(const bfrag*)&Ab[0];
    bfrag a1 = *(const bfrag*)&Ab[512];
    bfrag a2 = *(const bfrag*)&Ab[1024];
    bfrag a3 = *(const bfrag*)&Ab[1536];
    if (kt + 3 < NKT) STAGE_A(kt + 3);
    __builtin_amdgcn_s_setprio(1);
    MFMA_ROW(0, a0) MFMA_ROW(1, a1) MFMA_ROW(2, a2) MFMA_ROW(3, a3)
    __builtin_amdgcn_s_setprio(0);
    __builtin_amdgcn_s_barrier();
    asm volatile("" ::: "memory");

    // ---- phase 1: m4..7 x n0..3 (b reused)
    bfrag a4 = *(const bfrag*)&Ab[2048];
    bfrag a5 = *(const bfrag*)&Ab[2560];
    bfrag a6 = *(const bfrag*)&Ab[3072];
    bfrag a7 = *(const bfrag*)&Ab[3584];
    if (kt + 3 < NKT) STAGE_B(kt + 3);
    __builtin_amdgcn_s_setprio(1);
    MFMA_ROW(4, a4) MFMA_ROW(5, a5) MFMA_ROW(6, a6) MFMA_ROW(7, a7)
    __builtin_amdgcn_s_setprio(0);
  }

  const bool bf = flag[0] != 0;
  float* of = (float*)outp;
  unsigned short* oh = (unsigned short*)outp;
#pragma unroll
  for (int m = 0; m < 8; ++m)
#pragma unroll
    for (int n = 0; n < 4; ++n)
#pragma unroll
      for (int q = 0; q < 4; ++q) {
        int gr = tm + wr * 128 + m * 16 + kq * 4 + q;
        int gc = tn + wc * 64 + n * 16 + lr;
        float v = acc[m][n][q];
        if (!bf) of[(size_t)gr * D + gc] = v;
        else     oh[(size_t)gr * D + gc] = (unsigned short)f2bf(v);
      }
#undef STAGE_A
#undef STAGE_B
#undef MFMA_ROW
}

// ---------------------------------------------------------------- host
extern "C" void kernel_launch(void* const* d_in, const int* in_sizes, int n_in,
                              void* d_out, int out_size, void* d_ws, size_t ws_size,
                              hipStream_t stream) {
  const void* x  = d_in[0];
  const void* bw = d_in[1];
  const void* rw = d_in[2];
  const void* lA = d_in[3];
  const void* lB = d_in[4];

  char* ws = (char*)d_ws;
  const size_t XB_BYTES  = (size_t)NT * KX * 2;   // 69,206,016
  const size_t WB_BYTES  = (size_t)D * KX * 2;    // 34,603,008
  const size_t ABT_BYTES = (size_t)KE * D * 2;    //  1,048,576
  const size_t WD_BYTES  = (size_t)NT * NE * 4;   //    262,144
  const size_t NEED = 256 + XB_BYTES + WB_BYTES + ABT_BYTES + WD_BYTES;
  if (ws_size < NEED) return;  // cannot run without scratch

  int*   flag   = (int*)ws;
  short* Xb     = (short*)(ws + 256);
  short* Wb     = (short*)(ws + 256 + XB_BYTES);
  short* Abt    = (short*)(ws + 256 + XB_BYTES + WB_BYTES);
  float* wdense = (float*)(ws + 256 + XB_BYTES + WB_BYTES + ABT_BYTES);

  hipLaunchKernelGGL(moe_k_detect, dim3(1), dim3(64), 0, stream,
                     (const unsigned*)x, flag);
  hipLaunchKernelGGL(moe_k_prep, dim3(8336), dim3(256), 0, stream,
                     bw, lA, lB, flag, Wb, Abt);
  hipLaunchKernelGGL(moe_k_xrouter, dim3(NT / 4), dim3(256), 0, stream,
                     x, rw, flag, Xb, wdense);
  hipLaunchKernelGGL(moe_k_mid, dim3(NT / 32), dim3(256), 0, stream,
                     Xb, Abt, wdense, Xb);
  hipLaunchKernelGGL(moe_k_main8, dim3(512), dim3(512), 0, stream,
                     Xb, Wb, flag, d_out);
}

// Round 4
// 403.666 us; speedup vs baseline: 1.4042x; 1.0629x over previous
//
#include <hip/hip_runtime.h>
#include <math.h>

#define DI __device__ __forceinline__

typedef __attribute__((ext_vector_type(4))) float  f32x4;
typedef __attribute__((ext_vector_type(4))) short  s16x4;
typedef __attribute__((ext_vector_type(8))) short  s16x8;
typedef __attribute__((ext_vector_type(4))) float  ffrag;
typedef s16x8 bfrag;

constexpr int NT = 8192;   // B*S tokens
constexpr int D  = 4096;
constexpr int NE = 8;      // experts
constexpr int KE = 128;    // E * R
constexpr int KX = D + KE; // 4224 extended K

DI short f2bf(float f) {
  unsigned u = __builtin_bit_cast(unsigned, f);
  u += 0x7FFFu + ((u >> 16) & 1u);   // RNE
  return (short)(u >> 16);
}
DI float bf2f(short h) {
  unsigned u = ((unsigned)(unsigned short)h) << 16;
  return __builtin_bit_cast(float, u);
}

#define GLOAD16(gp, lp)                                                        \
  __builtin_amdgcn_global_load_lds(                                            \
      (const __attribute__((address_space(1))) void*)(gp),                     \
      (__attribute__((address_space(3))) void*)(lp), 16, 0, 0)

// ---------------------------------------------------------------- detect
__global__ void moe_k_detect(const unsigned* __restrict__ x, int* __restrict__ flag) {
  int l = threadIdx.x;
  int cnt = 0;
  for (int i = l; i < 2048; i += 64) {
    unsigned e = (x[i] >> 23) & 0xFFu;
    cnt += (e >= 110u && e <= 140u) ? 1 : 0;
  }
#pragma unroll
  for (int o = 32; o; o >>= 1) cnt += __shfl_xor(cnt, o);
  if (l == 0) flag[0] = (cnt > 1024) ? 0 : 1;
}

// ---------------------------------------------------------------- prep
__global__ __launch_bounds__(256)
void moe_k_prep(const void* __restrict__ wp, const void* __restrict__ lAp,
                const void* __restrict__ lBp, const int* __restrict__ flag,
                short* __restrict__ Wb, short* __restrict__ Abt) {
  const bool bf = flag[0] != 0;
  int b = blockIdx.x, t = threadIdx.x;
  if (b < 8192) {
    int tid = b * 256 + t;
    int row = tid >> 9;           // 0..4095
    int col = (tid & 511) << 3;   // 0..4088
    s16x8 o;
    if (!bf) {
      const float* Wf = (const float*)wp;
      f32x4 v0 = *(const f32x4*)&Wf[(size_t)row * 4096 + col];
      f32x4 v1 = *(const f32x4*)&Wf[(size_t)row * 4096 + col + 4];
      o[0] = f2bf(v0[0]); o[1] = f2bf(v0[1]); o[2] = f2bf(v0[2]); o[3] = f2bf(v0[3]);
      o[4] = f2bf(v1[0]); o[5] = f2bf(v1[1]); o[6] = f2bf(v1[2]); o[7] = f2bf(v1[3]);
    } else {
      o = *(const s16x8*)&((const short*)wp)[(size_t)row * 4096 + col];
    }
    *(s16x8*)&Wb[(size_t)row * KX + col] = o;
  } else if (b < 8208) {
    int d = (b - 8192) * 256 + t; // 0..4095
    for (int j0 = 0; j0 < KE; j0 += 8) {
      s16x8 o;
#pragma unroll
      for (int i = 0; i < 8; ++i) {
        float v = bf ? bf2f(((const short*)lBp)[(size_t)(j0 + i) * 4096 + d])
                     : ((const float*)lBp)[(size_t)(j0 + i) * 4096 + d];
        o[i] = f2bf(2.0f * v);    // SCALING folded here
      }
      *(s16x8*)&Wb[(size_t)d * KX + 4096 + j0] = o;
    }
  } else {
    int j = b - 8208;             // 0..127
    int e = j >> 4, r = j & 15;
    for (int d = t; d < 4096; d += 256) {
      size_t src = ((size_t)e * 4096 + d) * 16 + r;
      short v = bf ? ((const short*)lAp)[src] : f2bf(((const float*)lAp)[src]);
      Abt[(size_t)j * 4096 + d] = v;
    }
  }
}

// ---------------------------------------------------------------- x convert + router
__global__ __launch_bounds__(256)
void moe_k_xrouter(const void* __restrict__ xp, const void* __restrict__ rp,
                   const int* __restrict__ flag, short* __restrict__ Xb,
                   float* __restrict__ wdense) {
  const bool bf = flag[0] != 0;
  int t = threadIdx.x, wv = t >> 6, l = t & 63;
  int n = blockIdx.x * 4 + wv;
  float acc[NE];
#pragma unroll
  for (int e = 0; e < NE; ++e) acc[e] = 0.f;
  const float* xf = (const float*)xp;
  const short* xh = (const short*)xp;
  const float* rf = (const float*)rp;
  const short* rh = (const short*)rp;
  for (int it = 0; it < 16; ++it) {
    int d = it * 256 + l * 4;
    float x0, x1, x2, x3;
    s16x4 xo;
    if (!bf) {
      f32x4 v = *(const f32x4*)&xf[(size_t)n * D + d];
      x0 = v[0]; x1 = v[1]; x2 = v[2]; x3 = v[3];
      xo[0] = f2bf(x0); xo[1] = f2bf(x1); xo[2] = f2bf(x2); xo[3] = f2bf(x3);
    } else {
      xo = *(const s16x4*)&xh[(size_t)n * D + d];
      x0 = bf2f(xo[0]); x1 = bf2f(xo[1]); x2 = bf2f(xo[2]); x3 = bf2f(xo[3]);
    }
    *(s16x4*)&Xb[(size_t)n * KX + d] = xo;
#pragma unroll
    for (int e = 0; e < NE; ++e) {
      if (!bf) {
        f32x4 w = *(const f32x4*)&rf[(size_t)e * D + d];
        acc[e] += x0 * w[0] + x1 * w[1] + x2 * w[2] + x3 * w[3];
      } else {
        s16x4 w = *(const s16x4*)&rh[(size_t)e * D + d];
        acc[e] += x0 * bf2f(w[0]) + x1 * bf2f(w[1]) + x2 * bf2f(w[2]) + x3 * bf2f(w[3]);
      }
    }
  }
#pragma unroll
  for (int e = 0; e < NE; ++e) {
#pragma unroll
    for (int o = 32; o; o >>= 1) acc[e] += __shfl_xor(acc[e], o);
  }
  float m = acc[0];
#pragma unroll
  for (int e = 1; e < NE; ++e) m = fmaxf(m, acc[e]);
  float p[NE];
#pragma unroll
  for (int e = 0; e < NE; ++e) p[e] = __expf(acc[e] - m);
  int i1 = 0; float v1 = p[0];
#pragma unroll
  for (int e = 1; e < NE; ++e) { if (p[e] > v1) { v1 = p[e]; i1 = e; } }
  int i2 = 0; float v2 = -1.f;
#pragma unroll
  for (int e = 0; e < NE; ++e) { if (e != i1 && p[e] > v2) { v2 = p[e]; i2 = e; } }
  float inv = 1.f / (v1 + v2);
  if (l < NE) {
    float w = (l == i1) ? v1 * inv : ((l == i2) ? v2 * inv : 0.f);
    wdense[(size_t)n * NE + l] = w;
  }
}

// ---------------------------------------------------------------- mid GEMM v2 (pipelined)
// mid[n][j] = sum_d Xb[n][d]*Abt[j][d]; Xb[n][4096+j] = bf16(mid * w[n][j>>4]).
// Grid 256 blocks: blk>>1 -> 64-token tile, blk&1 -> 64-j tile. 4 waves (2x2),
// each wave 32 tok x 32 j. BK=32, ring-4 LDS (32KB), counted vmcnt (2 loads/
// thread/tile, uniform), 1 barrier/tile. MFMAs operand-swapped: lane holds
// token-row lr, 4 consecutive j -> lane-uniform expert weight + 8B stores.
__global__ __launch_bounds__(256)
void moe_k_mid2(const short* __restrict__ Xb, const short* __restrict__ Abt,
                const float* __restrict__ wdense, short* __restrict__ XbW) {
  __shared__ __align__(16) short LDS[16384];  // 4 x (A 4KB + B 4KB)
  const int t = threadIdx.x, l = t & 63, wv = t >> 6;
  const int wr = wv >> 1, wc = wv & 1;
  const int lr = l & 15, kq = l >> 4;
  const int m0 = (blockIdx.x >> 1) * 64;
  const int j0 = (blockIdx.x & 1) * 64;

  ffrag acc[2][2];
#pragma unroll
  for (int i = 0; i < 2; ++i)
#pragma unroll
    for (int j = 0; j < 2; ++j)
#pragma unroll
      for (int q = 0; q < 4; ++q) acc[i][j][q] = 0.f;

  const int srow = t >> 2, sslot = t & 3;  // staging: 4 threads/row, 64B/row
#define MSTAGE(kt_)                                                            \
  do {                                                                         \
    int _k0 = (kt_) * 32, _b = ((kt_) & 3) * 4096;                             \
    GLOAD16(&Xb[(size_t)(m0 + srow) * KX + _k0 + sslot * 8], &LDS[_b + t * 8]);\
    GLOAD16(&Abt[(size_t)(j0 + srow) * 4096 + _k0 + sslot * 8],                \
            &LDS[_b + 2048 + t * 8]);                                          \
  } while (0)

  MSTAGE(0); MSTAGE(1); MSTAGE(2);
  constexpr int NKT = 128;

  for (int kt = 0; kt < NKT; ++kt) {
    if (kt + 2 < NKT)      asm volatile("s_waitcnt vmcnt(4)" ::: "memory");
    else if (kt + 1 < NKT) asm volatile("s_waitcnt vmcnt(2)" ::: "memory");
    else                   asm volatile("s_waitcnt vmcnt(0)" ::: "memory");
    __builtin_amdgcn_s_barrier();
    __builtin_amdgcn_sched_barrier(0);

    const int bufs = (kt & 3) * 4096;
    const short* As = &LDS[bufs + (wr * 32 + lr) * 32 + kq * 8];
    const short* Bs = &LDS[bufs + 2048 + (wc * 32 + lr) * 32 + kq * 8];
    bfrag a0 = *(const bfrag*)&As[0];
    bfrag a1 = *(const bfrag*)&As[512];
    bfrag b0 = *(const bfrag*)&Bs[0];
    bfrag b1 = *(const bfrag*)&Bs[512];
    if (kt + 3 < NKT) MSTAGE(kt + 3);
    asm volatile("" ::: "memory");
    // operand-swapped: D.row -> j (first op), D.col -> token (second op)
    acc[0][0] = __builtin_amdgcn_mfma_f32_16x16x32_bf16(b0, a0, acc[0][0], 0, 0, 0);
    acc[0][1] = __builtin_amdgcn_mfma_f32_16x16x32_bf16(b1, a0, acc[0][1], 0, 0, 0);
    acc[1][0] = __builtin_amdgcn_mfma_f32_16x16x32_bf16(b0, a1, acc[1][0], 0, 0, 0);
    acc[1][1] = __builtin_amdgcn_mfma_f32_16x16x32_bf16(b1, a1, acc[1][1], 0, 0, 0);
  }

#pragma unroll
  for (int m = 0; m < 2; ++m)
#pragma unroll
    for (int n = 0; n < 2; ++n) {
      int gr = m0 + wr * 32 + m * 16 + lr;
      int jb = j0 + wc * 32 + n * 16 + kq * 4;
      int e  = jb >> 4;
      float w = wdense[(size_t)gr * NE + e];
      s16x4 o;
#pragma unroll
      for (int q = 0; q < 4; ++q) o[q] = f2bf(acc[m][n][q] * w);
      *(s16x4*)&XbW[(size_t)gr * KX + 4096 + jb] = o;
    }
#undef MSTAGE
}

// ---------------------------------------------------------------- main GEMM
// out[n][o] = sum_k Xb[n][k]*Wb[o][k], K=4224. 256x256 tile, BK=32, 8 waves
// (2M x 4N), ring-4 LDS (128KB), coalesced+xor-swizzled staging (R3, 0 confl).
// R4: template-style phases -- ds_reads issued BEFORE a barrier, consumed
// after (read latency overlaps other waves' MFMA drain); 3 barriers/tile;
// sched_barrier(0) pins (rule #18). MFMAs operand-swapped so lane holds 4
// consecutive out-columns -> dwordx4 epilogue stores (128 -> 32 store instrs).
__global__ __launch_bounds__(512, 2)
void moe_k_main8(const short* __restrict__ Xb, const short* __restrict__ Wb,
                 const int* __restrict__ flag, void* __restrict__ outp) {
  __shared__ __align__(16) short LDS[65536];  // 128 KiB
  const int t = threadIdx.x;
  const int l = t & 63;
  const int wv = t >> 6;
  const int wr = wv >> 2;        // 0..1  (M group: 128 rows)
  const int wc = wv & 3;         // 0..3  (N group: 64 cols)
  const int lr = l & 15;
  const int kq = l >> 4;         // 0..3

  int wg = blockIdx.x;                       // 512 wgs, %8==0 -> XCD swizzle
  int swz = (wg & 7) * 64 + (wg >> 3);
  const int tm = (swz >> 4) * 256;
  const int tn = (swz & 15) * 256;

  ffrag acc[8][4];
#pragma unroll
  for (int i = 0; i < 8; ++i)
#pragma unroll
    for (int j = 0; j < 4; ++j)
#pragma unroll
      for (int q = 0; q < 4; ++q) acc[i][j][q] = 0.f;

  // staging: chunk c -> row = c>>2, slot s = c&3, global kc = s ^ ((row>>1)&3)
#define STAGE_A(kt_)                                                           \
  do {                                                                         \
    int _k0 = (kt_) * 32, _b = ((kt_) & 3) * 16384;                            \
    _Pragma("unroll")                                                          \
    for (int _i = 0; _i < 2; ++_i) {                                           \
      int _c = _i * 512 + t;                                                   \
      int _r = _c >> 2;                                                        \
      int _kc = (_c & 3) ^ ((_r >> 1) & 3);                                    \
      GLOAD16(&Xb[(size_t)(tm + _r) * KX + _k0 + _kc * 8], &LDS[_b + _c * 8]); \
    }                                                                          \
  } while (0)
#define STAGE_B(kt_)                                                           \
  do {                                                                         \
    int _k0 = (kt_) * 32, _b = ((kt_) & 3) * 16384 + 8192;                     \
    _Pragma("unroll")                                                          \
    for (int _i = 0; _i < 2; ++_i) {                                           \
      int _c = _i * 512 + t;                                                   \
      int _r = _c >> 2;                                                        \
      int _kc = (_c & 3) ^ ((_r >> 1) & 3);                                    \
      GLOAD16(&Wb[(size_t)(tn + _r) * KX + _k0 + _kc * 8], &LDS[_b + _c * 8]); \
    }                                                                          \
  } while (0)

  STAGE_A(0); STAGE_B(0);
  STAGE_A(1); STAGE_B(1);
  STAGE_A(2); STAGE_B(2);

  constexpr int NKT = KX / 32;  // 132

  const int kx = kq ^ ((lr >> 1) & 3);           // swizzled 16B slot
  const int aofs = (wr * 128 + lr) * 32 + kx * 8;
  const int bofs = 8192 + (wc * 64 + lr) * 32 + kx * 8;

  // operand-swapped: first operand = B-frag (out col), second = A-frag (row)
#define MFMA_ROW(mi, av)                                                           \
  acc[mi][0] = __builtin_amdgcn_mfma_f32_16x16x32_bf16(b0, av, acc[mi][0], 0, 0, 0); \
  acc[mi][1] = __builtin_amdgcn_mfma_f32_16x16x32_bf16(b1, av, acc[mi][1], 0, 0, 0); \
  acc[mi][2] = __builtin_amdgcn_mfma_f32_16x16x32_bf16(b2, av, acc[mi][2], 0, 0, 0); \
  acc[mi][3] = __builtin_amdgcn_mfma_f32_16x16x32_bf16(b3, av, acc[mi][3], 0, 0, 0);

  for (int kt = 0; kt < NKT; ++kt) {
    // residency wait for tile kt (counted; never 0 in steady state)
    if (kt + 2 < NKT)      asm volatile("s_waitcnt vmcnt(8)" ::: "memory");
    else if (kt + 1 < NKT) asm volatile("s_waitcnt vmcnt(4)" ::: "memory");
    else                   asm volatile("s_waitcnt vmcnt(0)" ::: "memory");
    __builtin_amdgcn_s_barrier();
    __builtin_amdgcn_sched_barrier(0);

    const int bufs = (kt & 3) * 16384;
    const short* Ab = &LDS[bufs + aofs];
    const short* Bb = &LDS[bufs + bofs];

    // ---- phase A: issue reads + stage BEFORE barrier; MFMA after
    bfrag b0 = *(const bfrag*)&Bb[0];
    bfrag b1 = *(const bfrag*)&Bb[512];
    bfrag b2 = *(const bfrag*)&Bb[1024];
    bfrag b3 = *(const bfrag*)&Bb[1536];
    bfrag a0 = *(const bfrag*)&Ab[0];
    bfrag a1 = *(const bfrag*)&Ab[512];
    bfrag a2 = *(const bfrag*)&Ab[1024];
    bfrag a3 = *(const bfrag*)&Ab[1536];
    if (kt + 3 < NKT) STAGE_A(kt + 3);
    asm volatile("" ::: "memory");
    __builtin_amdgcn_s_barrier();
    __builtin_amdgcn_sched_barrier(0);
    __builtin_amdgcn_s_setprio(1);
    MFMA_ROW(0, a0) MFMA_ROW(1, a1) MFMA_ROW(2, a2) MFMA_ROW(3, a3)
    __builtin_amdgcn_s_setprio(0);

    // ---- phase B
    bfrag a4 = *(const bfrag*)&Ab[2048];
    bfrag a5 = *(const bfrag*)&Ab[2560];
    bfrag a6 = *(const bfrag*)&Ab[3072];
    bfrag a7 = *(const bfrag*)&Ab[3584];
    if (kt + 3 < NKT) STAGE_B(kt + 3);
    asm volatile("" ::: "memory");
    __builtin_amdgcn_s_barrier();
    __builtin_amdgcn_sched_barrier(0);
    __builtin_amdgcn_s_setprio(1);
    MFMA_ROW(4, a4) MFMA_ROW(5, a5) MFMA_ROW(6, a6) MFMA_ROW(7, a7)
    __builtin_amdgcn_s_setprio(0);
  }

  const bool bf = flag[0] != 0;
  float* of = (float*)outp;
  unsigned short* oh = (unsigned short*)outp;
#pragma unroll
  for (int m = 0; m < 8; ++m)
#pragma unroll
    for (int n = 0; n < 4; ++n) {
      int gr = tm + wr * 128 + m * 16 + lr;        // out row (2nd operand)
      int gc = tn + wc * 64 + n * 16 + kq * 4;     // out col base (1st operand)
      if (!bf) {
        *(f32x4*)&of[(size_t)gr * D + gc] = acc[m][n];
      } else {
        s16x4 o;
#pragma unroll
        for (int q = 0; q < 4; ++q) o[q] = f2bf(acc[m][n][q]);
        *(s16x4*)&oh[(size_t)gr * D + gc] = o;
      }
    }
#undef STAGE_A
#undef STAGE_B
#undef MFMA_ROW
}

// ---------------------------------------------------------------- host
extern "C" void kernel_launch(void* const* d_in, const int* in_sizes, int n_in,
                              void* d_out, int out_size, void* d_ws, size_t ws_size,
                              hipStream_t stream) {
  const void* x  = d_in[0];
  const void* bw = d_in[1];
  const void* rw = d_in[2];
  const void* lA = d_in[3];
  const void* lB = d_in[4];

  char* ws = (char*)d_ws;
  const size_t XB_BYTES  = (size_t)NT * KX * 2;   // 69,206,016
  const size_t WB_BYTES  = (size_t)D * KX * 2;    // 34,603,008
  const size_t ABT_BYTES = (size_t)KE * D * 2;    //  1,048,576
  const size_t WD_BYTES  = (size_t)NT * NE * 4;   //    262,144
  const size_t NEED = 256 + XB_BYTES + WB_BYTES + ABT_BYTES + WD_BYTES;
  if (ws_size < NEED) return;  // cannot run without scratch

  int*   flag   = (int*)ws;
  short* Xb     = (short*)(ws + 256);
  short* Wb     = (short*)(ws + 256 + XB_BYTES);
  short* Abt    = (short*)(ws + 256 + XB_BYTES + WB_BYTES);
  float* wdense = (float*)(ws + 256 + XB_BYTES + WB_BYTES + ABT_BYTES);

  hipLaunchKernelGGL(moe_k_detect, dim3(1), dim3(64), 0, stream,
                     (const unsigned*)x, flag);
  hipLaunchKernelGGL(moe_k_prep, dim3(8336), dim3(256), 0, stream,
                     bw, lA, lB, flag, Wb, Abt);
  hipLaunchKernelGGL(moe_k_xrouter, dim3(NT / 4), dim3(256), 0, stream,
                     x, rw, flag, Xb, wdense);
  hipLaunchKernelGGL(moe_k_mid2, dim3(256), dim3(256), 0, stream,
                     Xb, Abt, wdense, Xb);
  hipLaunchKernelGGL(moe_k_main8, dim3(512), dim3(512), 0, stream,
                     Xb, Wb, flag, d_out);
}

// Round 5
// 385.039 us; speedup vs baseline: 1.4721x; 1.0484x over previous
//
#include <hip/hip_runtime.h>
#include <math.h>

#define DI __device__ __forceinline__

typedef __attribute__((ext_vector_type(4))) float  f32x4;
typedef __attribute__((ext_vector_type(4))) short  s16x4;
typedef __attribute__((ext_vector_type(8))) short  s16x8;
typedef __attribute__((ext_vector_type(4))) float  ffrag;
typedef s16x8 bfrag;

constexpr int NT = 8192;   // B*S tokens
constexpr int D  = 4096;
constexpr int NE = 8;      // experts
constexpr int KE = 128;    // E * R
constexpr int KX = D + KE; // 4224 extended K

DI short f2bf(float f) {
  unsigned u = __builtin_bit_cast(unsigned, f);
  u += 0x7FFFu + ((u >> 16) & 1u);   // RNE
  return (short)(u >> 16);
}
DI float bf2f(short h) {
  unsigned u = ((unsigned)(unsigned short)h) << 16;
  return __builtin_bit_cast(float, u);
}

#define GLOAD16(gp, lp)                                                        \
  __builtin_amdgcn_global_load_lds(                                            \
      (const __attribute__((address_space(1))) void*)(gp),                     \
      (__attribute__((address_space(3))) void*)(lp), 16, 0, 0)

// ---------------------------------------------------------------- detect
__global__ void moe_k_detect(const unsigned* __restrict__ x, int* __restrict__ flag) {
  int l = threadIdx.x;
  int cnt = 0;
  for (int i = l; i < 2048; i += 64) {
    unsigned e = (x[i] >> 23) & 0xFFu;
    cnt += (e >= 110u && e <= 140u) ? 1 : 0;
  }
#pragma unroll
  for (int o = 32; o; o >>= 1) cnt += __shfl_xor(cnt, o);
  if (l == 0) flag[0] = (cnt > 1024) ? 0 : 1;
}

// ---------------------------------------------------------------- prep + xrouter (fused)
// blocks [0,8192):      Wb[d][0:4096] = bf16(base_W)
// blocks [8192,8208):   Wb[d][4096+j] = bf16(2 * lora_B[j][d])
// blocks [8208,8336):   Abt[j][d]     = bf16(lora_A[e][d][r])
// blocks [8336,10384):  x-convert + router for 4 tokens/block
__global__ __launch_bounds__(256)
void moe_k_prep_xr(const void* __restrict__ wp, const void* __restrict__ lAp,
                   const void* __restrict__ lBp, const void* __restrict__ xp,
                   const void* __restrict__ rp, const int* __restrict__ flag,
                   short* __restrict__ Wb, short* __restrict__ Abt,
                   short* __restrict__ Xb, float* __restrict__ wdense) {
  const bool bf = flag[0] != 0;
  int b = blockIdx.x, t = threadIdx.x;
  if (b < 8192) {
    int tid = b * 256 + t;
    int row = tid >> 9;
    int col = (tid & 511) << 3;
    s16x8 o;
    if (!bf) {
      const float* Wf = (const float*)wp;
      f32x4 v0 = *(const f32x4*)&Wf[(size_t)row * 4096 + col];
      f32x4 v1 = *(const f32x4*)&Wf[(size_t)row * 4096 + col + 4];
      o[0] = f2bf(v0[0]); o[1] = f2bf(v0[1]); o[2] = f2bf(v0[2]); o[3] = f2bf(v0[3]);
      o[4] = f2bf(v1[0]); o[5] = f2bf(v1[1]); o[6] = f2bf(v1[2]); o[7] = f2bf(v1[3]);
    } else {
      o = *(const s16x8*)&((const short*)wp)[(size_t)row * 4096 + col];
    }
    *(s16x8*)&Wb[(size_t)row * KX + col] = o;
  } else if (b < 8208) {
    int d = (b - 8192) * 256 + t;
    for (int j0 = 0; j0 < KE; j0 += 8) {
      s16x8 o;
#pragma unroll
      for (int i = 0; i < 8; ++i) {
        float v = bf ? bf2f(((const short*)lBp)[(size_t)(j0 + i) * 4096 + d])
                     : ((const float*)lBp)[(size_t)(j0 + i) * 4096 + d];
        o[i] = f2bf(2.0f * v);
      }
      *(s16x8*)&Wb[(size_t)d * KX + 4096 + j0] = o;
    }
  } else if (b < 8336) {
    int j = b - 8208;
    int e = j >> 4, r = j & 15;
    for (int d = t; d < 4096; d += 256) {
      size_t src = ((size_t)e * 4096 + d) * 16 + r;
      short v = bf ? ((const short*)lAp)[src] : f2bf(((const float*)lAp)[src]);
      Abt[(size_t)j * 4096 + d] = v;
    }
  } else {
    // ---- xrouter: one wave per token
    int wv = t >> 6, l = t & 63;
    int n = (b - 8336) * 4 + wv;
    float acc[NE];
#pragma unroll
    for (int e = 0; e < NE; ++e) acc[e] = 0.f;
    const float* xf = (const float*)xp;
    const short* xh = (const short*)xp;
    const float* rf = (const float*)rp;
    const short* rh = (const short*)rp;
    for (int it = 0; it < 16; ++it) {
      int d = it * 256 + l * 4;
      float x0, x1, x2, x3;
      s16x4 xo;
      if (!bf) {
        f32x4 v = *(const f32x4*)&xf[(size_t)n * D + d];
        x0 = v[0]; x1 = v[1]; x2 = v[2]; x3 = v[3];
        xo[0] = f2bf(x0); xo[1] = f2bf(x1); xo[2] = f2bf(x2); xo[3] = f2bf(x3);
      } else {
        xo = *(const s16x4*)&xh[(size_t)n * D + d];
        x0 = bf2f(xo[0]); x1 = bf2f(xo[1]); x2 = bf2f(xo[2]); x3 = bf2f(xo[3]);
      }
      *(s16x4*)&Xb[(size_t)n * KX + d] = xo;
#pragma unroll
      for (int e = 0; e < NE; ++e) {
        if (!bf) {
          f32x4 w = *(const f32x4*)&rf[(size_t)e * D + d];
          acc[e] += x0 * w[0] + x1 * w[1] + x2 * w[2] + x3 * w[3];
        } else {
          s16x4 w = *(const s16x4*)&rh[(size_t)e * D + d];
          acc[e] += x0 * bf2f(w[0]) + x1 * bf2f(w[1]) + x2 * bf2f(w[2]) + x3 * bf2f(w[3]);
        }
      }
    }
#pragma unroll
    for (int e = 0; e < NE; ++e) {
#pragma unroll
      for (int o = 32; o; o >>= 1) acc[e] += __shfl_xor(acc[e], o);
    }
    float m = acc[0];
#pragma unroll
    for (int e = 1; e < NE; ++e) m = fmaxf(m, acc[e]);
    float p[NE];
#pragma unroll
    for (int e = 0; e < NE; ++e) p[e] = __expf(acc[e] - m);
    int i1 = 0; float v1 = p[0];
#pragma unroll
    for (int e = 1; e < NE; ++e) { if (p[e] > v1) { v1 = p[e]; i1 = e; } }
    int i2 = 0; float v2 = -1.f;
#pragma unroll
    for (int e = 0; e < NE; ++e) { if (e != i1 && p[e] > v2) { v2 = p[e]; i2 = e; } }
    float inv = 1.f / (v1 + v2);
    if (l < NE) {
      float w = (l == i1) ? v1 * inv : ((l == i2) ? v2 * inv : 0.f);
      wdense[(size_t)n * NE + l] = w;
    }
  }
}

// ---------------------------------------------------------------- mid GEMM v2 (unchanged, R4)
__global__ __launch_bounds__(256)
void moe_k_mid2(const short* __restrict__ Xb, const short* __restrict__ Abt,
                const float* __restrict__ wdense, short* __restrict__ XbW) {
  __shared__ __align__(16) short LDS[16384];
  const int t = threadIdx.x, l = t & 63, wv = t >> 6;
  const int wr = wv >> 1, wc = wv & 1;
  const int lr = l & 15, kq = l >> 4;
  const int m0 = (blockIdx.x >> 1) * 64;
  const int j0 = (blockIdx.x & 1) * 64;

  ffrag acc[2][2];
#pragma unroll
  for (int i = 0; i < 2; ++i)
#pragma unroll
    for (int j = 0; j < 2; ++j)
#pragma unroll
      for (int q = 0; q < 4; ++q) acc[i][j][q] = 0.f;

  const int srow = t >> 2, sslot = t & 3;
#define MSTAGE(kt_)                                                            \
  do {                                                                         \
    int _k0 = (kt_) * 32, _b = ((kt_) & 3) * 4096;                             \
    GLOAD16(&Xb[(size_t)(m0 + srow) * KX + _k0 + sslot * 8], &LDS[_b + t * 8]);\
    GLOAD16(&Abt[(size_t)(j0 + srow) * 4096 + _k0 + sslot * 8],                \
            &LDS[_b + 2048 + t * 8]);                                          \
  } while (0)

  MSTAGE(0); MSTAGE(1); MSTAGE(2);
  constexpr int NKT = 128;

  for (int kt = 0; kt < NKT; ++kt) {
    if (kt + 2 < NKT)      asm volatile("s_waitcnt vmcnt(4)" ::: "memory");
    else if (kt + 1 < NKT) asm volatile("s_waitcnt vmcnt(2)" ::: "memory");
    else                   asm volatile("s_waitcnt vmcnt(0)" ::: "memory");
    __builtin_amdgcn_s_barrier();
    __builtin_amdgcn_sched_barrier(0);

    const int bufs = (kt & 3) * 4096;
    const short* As = &LDS[bufs + (wr * 32 + lr) * 32 + kq * 8];
    const short* Bs = &LDS[bufs + 2048 + (wc * 32 + lr) * 32 + kq * 8];
    bfrag a0 = *(const bfrag*)&As[0];
    bfrag a1 = *(const bfrag*)&As[512];
    bfrag b0 = *(const bfrag*)&Bs[0];
    bfrag b1 = *(const bfrag*)&Bs[512];
    if (kt + 3 < NKT) MSTAGE(kt + 3);
    asm volatile("" ::: "memory");
    acc[0][0] = __builtin_amdgcn_mfma_f32_16x16x32_bf16(b0, a0, acc[0][0], 0, 0, 0);
    acc[0][1] = __builtin_amdgcn_mfma_f32_16x16x32_bf16(b1, a0, acc[0][1], 0, 0, 0);
    acc[1][0] = __builtin_amdgcn_mfma_f32_16x16x32_bf16(b0, a1, acc[1][0], 0, 0, 0);
    acc[1][1] = __builtin_amdgcn_mfma_f32_16x16x32_bf16(b1, a1, acc[1][1], 0, 0, 0);
  }

#pragma unroll
  for (int m = 0; m < 2; ++m)
#pragma unroll
    for (int n = 0; n < 2; ++n) {
      int gr = m0 + wr * 32 + m * 16 + lr;
      int jb = j0 + wc * 32 + n * 16 + kq * 4;
      int e  = jb >> 4;
      float w = wdense[(size_t)gr * NE + e];
      s16x4 o;
#pragma unroll
      for (int q = 0; q < 4; ++q) o[q] = f2bf(acc[m][n][q] * w);
      *(s16x4*)&XbW[(size_t)gr * KX + 4096 + jb] = o;
    }
#undef MSTAGE
}

// ---------------------------------------------------------------- main GEMM v3
// 256x256 tile, BK=32, 8 waves (2Mx4N), ring-4 LDS, coalesced+xor-swizzled
// staging (R3, 0 conflicts). R5: one-phase-deep REGISTER pipeline -- frag
// ds_reads for phase p+1 issued before phase p's MFMA cluster so the LDS unit
// (≈1150 cyc/tile) and the matrix pipe (≈1240 cyc/tile) overlap instead of
// serializing. Lead-2 residency: vmcnt(4) at tile boundary => kt AND kt+1
// resident, legalizing mid-tile next-tile reads. 1 barrier/tile.
__global__ __launch_bounds__(512, 2)
void moe_k_main8(const short* __restrict__ Xb, const short* __restrict__ Wb,
                 const int* __restrict__ flag, void* __restrict__ outp) {
  __shared__ __align__(16) short LDS[65536];  // 128 KiB: ring-4 x (A 16KB + B 16KB)
  const int t = threadIdx.x;
  const int l = t & 63;
  const int wv = t >> 6;
  const int wr = wv >> 2;
  const int wc = wv & 3;
  const int lr = l & 15;
  const int kq = l >> 4;

  int wg = blockIdx.x;
  int swz = (wg & 7) * 64 + (wg >> 3);
  const int tm = (swz >> 4) * 256;
  const int tn = (swz & 15) * 256;

  ffrag acc[8][4];
#pragma unroll
  for (int i = 0; i < 8; ++i)
#pragma unroll
    for (int j = 0; j < 4; ++j)
#pragma unroll
      for (int q = 0; q < 4; ++q) acc[i][j][q] = 0.f;

#define STAGE_A(kt_)                                                           \
  do {                                                                         \
    int _k0 = (kt_) * 32, _b = ((kt_) & 3) * 16384;                            \
    _Pragma("unroll")                                                          \
    for (int _i = 0; _i < 2; ++_i) {                                           \
      int _c = _i * 512 + t;                                                   \
      int _r = _c >> 2;                                                        \
      int _kc = (_c & 3) ^ ((_r >> 1) & 3);                                    \
      GLOAD16(&Xb[(size_t)(tm + _r) * KX + _k0 + _kc * 8], &LDS[_b + _c * 8]); \
    }                                                                          \
  } while (0)
#define STAGE_B(kt_)                                                           \
  do {                                                                         \
    int _k0 = (kt_) * 32, _b = ((kt_) & 3) * 16384 + 8192;                     \
    _Pragma("unroll")                                                          \
    for (int _i = 0; _i < 2; ++_i) {                                           \
      int _c = _i * 512 + t;                                                   \
      int _r = _c >> 2;                                                        \
      int _kc = (_c & 3) ^ ((_r >> 1) & 3);                                    \
      GLOAD16(&Wb[(size_t)(tn + _r) * KX + _k0 + _kc * 8], &LDS[_b + _c * 8]); \
    }                                                                          \
  } while (0)

  STAGE_A(0); STAGE_B(0);
  STAGE_A(1); STAGE_B(1);
  STAGE_A(2); STAGE_B(2);

  constexpr int NKT = KX / 32;  // 132

  const int kx = kq ^ ((lr >> 1) & 3);
  const int aofs = (wr * 128 + lr) * 32 + kx * 8;
  const int bofs = 8192 + (wc * 64 + lr) * 32 + kx * 8;

  // frag sets: C = current tile, N = next tile (ping-pong via x2 unroll)
  bfrag bA[4], aA[8], bB[4], aB[8];

  // prologue: tiles 0,1 resident after vmcnt(4); load tile-0 phase-A frags
  asm volatile("s_waitcnt vmcnt(4)" ::: "memory");
  __builtin_amdgcn_s_barrier();
  asm volatile("" ::: "memory");
  {
    const short* Ab0 = &LDS[aofs];
    const short* Bb0 = &LDS[bofs];
#pragma unroll
    for (int i = 0; i < 4; ++i) bA[i] = *(const bfrag*)&Bb0[i * 512];
#pragma unroll
    for (int i = 0; i < 4; ++i) aA[i] = *(const bfrag*)&Ab0[i * 512];
  }

  // one tile: CURB/CURA consumed; NXTB/NXTA loaded (unless LAST)
#define TILE_BODY(kt_, CURB, CURA, NXTB, NXTA, LAST)                           \
  {                                                                            \
    const int _slc = ((kt_) & 3) * 16384;                                      \
    const short* _AbC = &LDS[_slc + aofs];                                     \
    _Pragma("unroll")                                                          \
    for (int _i = 0; _i < 4; ++_i)                                             \
      CURA[4 + _i] = *(const bfrag*)&_AbC[2048 + _i * 512];                    \
    if ((kt_) + 3 < NKT) STAGE_A((kt_) + 3);                                   \
    __builtin_amdgcn_sched_barrier(0);                                         \
    __builtin_amdgcn_s_setprio(1);                                             \
    _Pragma("unroll")                                                          \
    for (int _m = 0; _m < 4; ++_m)                                             \
      _Pragma("unroll")                                                        \
      for (int _n = 0; _n < 4; ++_n)                                           \
        acc[_m][_n] = __builtin_amdgcn_mfma_f32_16x16x32_bf16(                 \
            CURB[_n], CURA[_m], acc[_m][_n], 0, 0, 0);                         \
    __builtin_amdgcn_s_setprio(0);                                             \
    if (!(LAST)) {                                                             \
      const int _sln = (((kt_) + 1) & 3) * 16384;                              \
      const short* _AbN = &LDS[_sln + aofs];                                   \
      const short* _BbN = &LDS[_sln + bofs];                                   \
      _Pragma("unroll")                                                        \
      for (int _i = 0; _i < 4; ++_i) NXTB[_i] = *(const bfrag*)&_BbN[_i * 512];\
      _Pragma("unroll")                                                        \
      for (int _i = 0; _i < 4; ++_i) NXTA[_i] = *(const bfrag*)&_AbN[_i * 512];\
    }                                                                          \
    if ((kt_) + 3 < NKT) STAGE_B((kt_) + 3);                                   \
    __builtin_amdgcn_sched_barrier(0);                                         \
    __builtin_amdgcn_s_setprio(1);                                             \
    _Pragma("unroll")                                                          \
    for (int _m = 4; _m < 8; ++_m)                                             \
      _Pragma("unroll")                                                        \
      for (int _n = 0; _n < 4; ++_n)                                           \
        acc[_m][_n] = __builtin_amdgcn_mfma_f32_16x16x32_bf16(                 \
            CURB[_n], CURA[_m], acc[_m][_n], 0, 0, 0);                         \
    __builtin_amdgcn_s_setprio(0);                                             \
    if (!(LAST)) {                                                             \
      if ((kt_) + 4 < NKT) { asm volatile("s_waitcnt vmcnt(4)" ::: "memory"); }\
      else                 { asm volatile("s_waitcnt vmcnt(0)" ::: "memory"); }\
      __builtin_amdgcn_s_barrier();                                            \
      asm volatile("" ::: "memory");                                          \
    }                                                                          \
  }

  for (int kt = 0; kt < NKT; kt += 2) {
    TILE_BODY(kt,     bA, aA, bB, aB, false);
    TILE_BODY(kt + 1, bB, aB, bA, aA, (kt + 2 >= NKT));
  }

  const bool bf = flag[0] != 0;
  float* of = (float*)outp;
  unsigned short* oh = (unsigned short*)outp;
#pragma unroll
  for (int m = 0; m < 8; ++m)
#pragma unroll
    for (int n = 0; n < 4; ++n) {
      int gr = tm + wr * 128 + m * 16 + lr;
      int gc = tn + wc * 64 + n * 16 + kq * 4;
      if (!bf) {
        *(f32x4*)&of[(size_t)gr * D + gc] = acc[m][n];
      } else {
        s16x4 o;
#pragma unroll
        for (int q = 0; q < 4; ++q) o[q] = f2bf(acc[m][n][q]);
        *(s16x4*)&oh[(size_t)gr * D + gc] = o;
      }
    }
#undef STAGE_A
#undef STAGE_B
#undef TILE_BODY
}

// ---------------------------------------------------------------- host
extern "C" void kernel_launch(void* const* d_in, const int* in_sizes, int n_in,
                              void* d_out, int out_size, void* d_ws, size_t ws_size,
                              hipStream_t stream) {
  const void* x  = d_in[0];
  const void* bw = d_in[1];
  const void* rw = d_in[2];
  const void* lA = d_in[3];
  const void* lB = d_in[4];

  char* ws = (char*)d_ws;
  const size_t XB_BYTES  = (size_t)NT * KX * 2;
  const size_t WB_BYTES  = (size_t)D * KX * 2;
  const size_t ABT_BYTES = (size_t)KE * D * 2;
  const size_t WD_BYTES  = (size_t)NT * NE * 4;
  const size_t NEED = 256 + XB_BYTES + WB_BYTES + ABT_BYTES + WD_BYTES;
  if (ws_size < NEED) return;

  int*   flag   = (int*)ws;
  short* Xb     = (short*)(ws + 256);
  short* Wb     = (short*)(ws + 256 + XB_BYTES);
  short* Abt    = (short*)(ws + 256 + XB_BYTES + WB_BYTES);
  float* wdense = (float*)(ws + 256 + XB_BYTES + WB_BYTES + ABT_BYTES);

  hipLaunchKernelGGL(moe_k_detect, dim3(1), dim3(64), 0, stream,
                     (const unsigned*)x, flag);
  hipLaunchKernelGGL(moe_k_prep_xr, dim3(10384), dim3(256), 0, stream,
                     bw, lA, lB, x, rw, flag, Wb, Abt, Xb, wdense);
  hipLaunchKernelGGL(moe_k_mid2, dim3(256), dim3(256), 0, stream,
                     Xb, Abt, wdense, Xb);
  hipLaunchKernelGGL(moe_k_main8, dim3(512), dim3(512), 0, stream,
                     Xb, Wb, flag, d_out);
}